// Round 14
// baseline (627.591 us; speedup 1.0000x reference)
//
#include <hip/hip_runtime.h>
#include <math.h>

#define EPSV 1e-5f

typedef _Float16 f16;
typedef _Float16 f16x8 __attribute__((ext_vector_type(8)));
typedef _Float16 f16x4 __attribute__((ext_vector_type(4)));
typedef float f32x4 __attribute__((ext_vector_type(4)));

typedef const __attribute__((address_space(1))) void* as1_cvp;
typedef __attribute__((address_space(3))) void* as3_vp;
__device__ __forceinline__ void load_lds16(const void* g, void* l) {
    __builtin_amdgcn_global_load_lds((as1_cvp)g, (as3_vp)l, 16, 0, 0);
}

static constexpr int GROUP_N = 16 * 16 * 2048;   // elems per (b,g) group

// ---------------- T1: fused stats + raw-f16 transpose ----------------
__global__ __launch_bounds__(256) void k_xtstat(const float* __restrict__ x,
                                                f16* __restrict__ xT,
                                                float* __restrict__ psum2,
                                                float* __restrict__ psq2) {
    const int x0 = blockIdx.x * 64;
    const int c0 = blockIdx.y * 64;
    const int b  = blockIdx.z >> 4, t = blockIdx.z & 15;
    const int tid = threadIdx.x;
    __shared__ float tile[64][68];
#pragma unroll
    for (int it = 0; it < 4; ++it) {
        int idx = it * 256 + tid;            // 0..1023
        int c = idx >> 4, xq = idx & 15;
        float4 v = *(const float4*)(x + (((size_t)(b * 512 + c0 + c) * 16 + t) * 2048) + x0 + xq * 4);
        tile[c][xq * 4 + 0] = v.x;
        tile[c][xq * 4 + 1] = v.y;
        tile[c][xq * 4 + 2] = v.z;
        tile[c][xq * 4 + 3] = v.w;
    }
    __syncthreads();
#pragma unroll
    for (int it = 0; it < 2; ++it) {
        int idx = it * 256 + tid;            // 0..511
        int xr = idx >> 3, ch = idx & 7;
        f16x8 h;
#pragma unroll
        for (int e = 0; e < 8; ++e) h[e] = (f16)tile[ch * 8 + e][xr];
        *(f16x8*)(xT + (((size_t)(b * 2048 + x0 + xr) * 16 + t) * 512) + c0 + ch * 8) = h;
    }
    {
        const int gg = tid >> 6, lane = tid & 63;
        float s = 0.f, q = 0.f;
#pragma unroll
        for (int i = 0; i < 16; ++i) {
            float v = tile[gg * 16 + i][lane];
            s += v; q += v * v;
        }
#pragma unroll
        for (int off = 32; off > 0; off >>= 1) {
            s += __shfl_down(s, off);
            q += __shfl_down(q, off);
        }
        if (lane == 0) {
            int grp = b * 32 + blockIdx.y * 4 + gg;
            int col = blockIdx.x * 16 + t;
            psum2[grp * 512 + col] = s;
            psq2[grp * 512 + col] = q;
        }
    }
}

__global__ void k_gn_final2(const float* __restrict__ psum2, const float* __restrict__ psq2,
                            float* __restrict__ mu, float* __restrict__ rs) {
    const int t = threadIdx.x;  // 0..127
    float s = 0.f, q = 0.f;
    const float* ps = psum2 + t * 512;
    const float* pq = psq2 + t * 512;
#pragma unroll 4
    for (int i = 0; i < 512; i += 4) {
        float4 a = *(const float4*)(ps + i);
        float4 c = *(const float4*)(pq + i);
        s += a.x + a.y + a.z + a.w;
        q += c.x + c.y + c.z + c.w;
    }
    const float m = s / (float)GROUP_N;
    float v = q / (float)GROUP_N - m * m;
    mu[t] = m;
    rs[t] = 1.0f / sqrtf(v + EPSV);
}

// ---------------- T2/T3 stats ----------------
__global__ __launch_bounds__(256) void k_gn_part(const float* __restrict__ x,
                                                 float* __restrict__ psum,
                                                 float* __restrict__ psq) {
    const int blk = blockIdx.x;
    const int tid = threadIdx.x;
    const float* p = x + (size_t)blk * 32768;
    float s = 0.f, q = 0.f;
#pragma unroll
    for (int i = 0; i < 32; ++i) {
        float4 v = *(const float4*)(p + (size_t)(i * 256 + tid) * 4);
        s += v.x + v.y + v.z + v.w;
        q += v.x * v.x + v.y * v.y + v.z * v.z + v.w * v.w;
    }
#pragma unroll
    for (int off = 32; off > 0; off >>= 1) {
        s += __shfl_down(s, off);
        q += __shfl_down(q, off);
    }
    __shared__ float ls[4], lq[4];
    const int wave = tid >> 6, lane = tid & 63;
    if (lane == 0) { ls[wave] = s; lq[wave] = q; }
    __syncthreads();
    if (tid == 0) {
        psum[blk] = ls[0] + ls[1] + ls[2] + ls[3];
        psq[blk]  = lq[0] + lq[1] + lq[2] + lq[3];
    }
}

__global__ void k_gn_final(const float* __restrict__ psum, const float* __restrict__ psq,
                           float* __restrict__ mu, float* __restrict__ rs) {
    const int t = threadIdx.x;  // 0..127
    float s = 0.f, q = 0.f;
#pragma unroll
    for (int i = 0; i < 16; ++i) { s += psum[t * 16 + i]; q += psq[t * 16 + i]; }
    const float m = s / (float)GROUP_N;
    float v = q / (float)GROUP_N - m * m;
    mu[t] = m;
    rs[t] = 1.0f / sqrtf(v + EPSV);
}

__global__ __launch_bounds__(256) void k_fold_sc(const float* __restrict__ gn_w,
                                                 const float* __restrict__ gn_b,
                                                 const float* __restrict__ mu,
                                                 const float* __restrict__ rs,
                                                 float* __restrict__ sc,
                                                 float* __restrict__ beta) {
    const int u = blockIdx.x * 256 + threadIdx.x;  // 0..2047
    const int b = u >> 9, c = u & 511;
    const int g = c >> 4;
    const float r = rs[b * 32 + g], m = mu[b * 32 + g];
    const float s = r * gn_w[c];
    sc[u]   = s;
    beta[u] = gn_b[c] - m * s;
}

__global__ __launch_bounds__(256) void k_fold_bias(const float* __restrict__ qkv_w,
                                                   const float* __restrict__ qkv_b,
                                                   const float* __restrict__ beta,
                                                   float* __restrict__ qbias) {
    const int u = blockIdx.x * 256 + threadIdx.x;  // 0..6143
    const int b = u / 1536, o = u % 1536;
    float acc = qkv_b[o];
    const float* wr = qkv_w + (size_t)o * 512;
    const float* be = beta + b * 512;
#pragma unroll 4
    for (int c = 0; c < 512; c += 4) {
        float4 w4 = *(const float4*)(wr + c);
        float4 b4 = *(const float4*)(be + c);
        acc += w4.x * b4.x + w4.y * b4.y + w4.z * b4.z + w4.w * b4.w;
    }
    if (o >= 512 && o < 1024) acc *= 0.125f;
    qbias[u] = acc;
}

__global__ __launch_bounds__(256) void k_prep_wb(const float* __restrict__ qkv_w,
                                                 const float* __restrict__ sc,
                                                 f16* __restrict__ w16b) {
    const int id = blockIdx.x * 256 + threadIdx.x;  // 0..196607
    const int b  = blockIdx.y;
    const int e0 = id * 4;
    const int o  = e0 >> 9;
    const float ksc = (o >= 512 && o < 1024) ? 0.125f : 1.0f;
    float4 wv = *(const float4*)(qkv_w + e0);
    float4 s4 = *(const float4*)(sc + b * 512 + (e0 & 511));
    f16x4 h = { (f16)(wv.x * s4.x * ksc), (f16)(wv.y * s4.y * ksc),
                (f16)(wv.z * s4.z * ksc), (f16)(wv.w * s4.w * ksc) };
    *(f16x4*)(w16b + (size_t)b * 786432 + e0) = h;
}

__global__ __launch_bounds__(256) void k_prep_p(const float* __restrict__ proj_w,
                                                f16* __restrict__ p16) {
    const int id = blockIdx.x * 256 + threadIdx.x;  // 0..65535
    const int e0 = id * 4;
    float4 v = *(const float4*)(proj_w + e0);
    f16x4 h = { (f16)v.x, (f16)v.y, (f16)v.z, (f16)v.w };
    *(f16x4*)(p16 + e0) = h;
}

__global__ __launch_bounds__(256) void k_prep_w(const float* __restrict__ qkv_w,
                                                const float* __restrict__ proj_w,
                                                f16* __restrict__ w16,
                                                f16* __restrict__ p16) {
    const int id = blockIdx.x * 256 + threadIdx.x;  // 0..262143
    if (id < 196608) {
        const int e0 = id * 4;
        const int o  = e0 >> 9;
        const float ksc = (o >= 512 && o < 1024) ? 0.125f : 1.0f;
        float4 v = *(const float4*)(qkv_w + e0);
        f16x4 h = { (f16)(v.x * ksc), (f16)(v.y * ksc), (f16)(v.z * ksc), (f16)(v.w * ksc) };
        *(f16x4*)(w16 + e0) = h;
    } else {
        const int e0 = (id - 196608) * 4;
        float4 v = *(const float4*)(proj_w + e0);
        f16x4 h = { (f16)v.x, (f16)v.y, (f16)v.z, (f16)v.w };
        *(f16x4*)(p16 + e0) = h;
    }
}

__global__ __launch_bounds__(256) void k_xt(const float* __restrict__ x,
                                            const float* __restrict__ sc,
                                            const float* __restrict__ beta,
                                            f16* __restrict__ xT) {
    const int x0 = blockIdx.x * 64;
    const int c0 = blockIdx.y * 64;
    const int b  = blockIdx.z >> 4, t = blockIdx.z & 15;
    const int tid = threadIdx.x;
    __shared__ float tile[64][68];
#pragma unroll
    for (int it = 0; it < 4; ++it) {
        int idx = it * 256 + tid;            // 0..1023
        int c = idx >> 4, xq = idx & 15;
        int cg = c0 + c;
        float s = sc[b * 512 + cg], be = beta[b * 512 + cg];
        float4 v = *(const float4*)(x + (((size_t)(b * 512 + cg) * 16 + t) * 2048) + x0 + xq * 4);
        tile[c][xq * 4 + 0] = v.x * s + be;
        tile[c][xq * 4 + 1] = v.y * s + be;
        tile[c][xq * 4 + 2] = v.z * s + be;
        tile[c][xq * 4 + 3] = v.w * s + be;
    }
    __syncthreads();
#pragma unroll
    for (int it = 0; it < 2; ++it) {
        int idx = it * 256 + tid;            // 0..511
        int xr = idx >> 3, ch = idx & 7;
        f16x8 h;
#pragma unroll
        for (int e = 0; e < 8; ++e) h[e] = (f16)tile[ch * 8 + e][xr];
        *(f16x8*)(xT + (((size_t)(b * 2048 + x0 + xr) * 16 + t) * 512) + c0 + ch * 8) = h;
    }
}

// ---- k3_mfma: fused QKV GEMM + MFMA attention, 16-x window, 8 waves ----
// Grid dim3(8,128,4), 512 thr: h = XCD (W_h slab L2-resident per XCD).
// Block tile 192x256: LDS reads per 768 MFMAs = 112KB (0.146 KB/MFMA,
// -30% vs N=128) -> attacks the measured LDS-read-throughput bound.
// gload_lds dbuf (async, issued before the compute phase), 1 barrier/k-step.
// Dyn LDS 128KB (dbuf 2x56KB; attention qkvT[256n][256m] f16 overlays).
// Attention output -> attnT f16 directly (full 128B sectors; R10-proven).
__global__ __launch_bounds__(512, 1) void k3_mfma(const f16* __restrict__ xT,
                                                  const f16* __restrict__ wsrc,
                                                  size_t w_bstride,
                                                  const float* __restrict__ qkv_b,
                                                  const float* __restrict__ qb_full,
                                                  const float* __restrict__ pos_emb,
                                                  f16* __restrict__ aT) {
    extern __shared__ __attribute__((aligned(16))) char smem[];
    const int h  = blockIdx.x;
    const int x0 = blockIdx.y * 16;
    const int b  = blockIdx.z;
    const int tid = threadIdx.x;
    const int lane = tid & 63, w = tid >> 6;   // 8 waves
    const int wm = w >> 2, wn = w & 3;         // 2M x 4N
    const int t_l = lane & 15, g = lane >> 4;

    const f16* xTb = xT + ((size_t)b * 2048 + x0) * 16 * 512;
    const f16* Wb  = wsrc + (size_t)b * w_bstride;

    const int l8 = (tid >> 3) & 7;
    const int gc = (tid & 7) ^ l8;             // pre-swizzled global chunk

    f32x4 acc[6][4];
#pragma unroll
    for (int mi = 0; mi < 6; ++mi)
#pragma unroll
        for (int ni = 0; ni < 4; ++ni) acc[mi][ni] = (f32x4){0.f, 0.f, 0.f, 0.f};

    // stage tile 0 -> buffer 0 (A: 1536 chunks = 3 iters; B: 2048 = 4 iters)
    {
#pragma unroll
        for (int it = 0; it < 3; ++it) {
            int s = it * 512 + tid;
            int m = s >> 3;
            int o = (m >> 6) * 512 + h * 64 + (m & 63);
            load_lds16(Wb + (size_t)o * 512 + gc * 8, smem + s * 16);
        }
#pragma unroll
        for (int it = 0; it < 4; ++it) {
            int s = it * 512 + tid;
            int n = s >> 3;
            load_lds16(xTb + (size_t)n * 512 + gc * 8, smem + 24576 + s * 16);
        }
    }
    __syncthreads();

    int cur = 0;
    for (int ks = 0; ks < 8; ++ks) {
        if (ks < 7) {
            char* bufn = smem + (cur ^ 1) * 57344;
            const int kon = (ks + 1) * 64;
#pragma unroll
            for (int it = 0; it < 3; ++it) {
                int s = it * 512 + tid;
                int m = s >> 3;
                int o = (m >> 6) * 512 + h * 64 + (m & 63);
                load_lds16(Wb + (size_t)o * 512 + kon + gc * 8, bufn + s * 16);
            }
#pragma unroll
            for (int it = 0; it < 4; ++it) {
                int s = it * 512 + tid;
                int n = s >> 3;
                load_lds16(xTb + (size_t)n * 512 + kon + gc * 8, bufn + 24576 + s * 16);
            }
        }
        const char* bufc = smem + cur * 57344;
        const f16* a_s = (const f16*)bufc;
        const f16* b_s = (const f16*)(bufc + 24576);
#pragma unroll
        for (int kk = 0; kk < 2; ++kk) {
            const int kb = kk * 4 + g;
            f16x8 af[6], bf[4];
#pragma unroll
            for (int mi = 0; mi < 6; ++mi) {
                int m = wm * 96 + mi * 16 + t_l;
                af[mi] = *(const f16x8*)(a_s + m * 64 + ((kb ^ (m & 7)) * 8));
            }
#pragma unroll
            for (int ni = 0; ni < 4; ++ni) {
                int n = wn * 64 + ni * 16 + t_l;
                bf[ni] = *(const f16x8*)(b_s + n * 64 + ((kb ^ (n & 7)) * 8));
            }
#pragma unroll
            for (int mi = 0; mi < 6; ++mi)
#pragma unroll
                for (int ni = 0; ni < 4; ++ni)
                    acc[mi][ni] = __builtin_amdgcn_mfma_f32_16x16x32_f16(af[mi], bf[ni], acc[mi][ni], 0, 0, 0);
        }
        __syncthreads();
        cur ^= 1;
    }

    // epilogue: acc + bias -> qkvT[n][m] f16, swizzled chunks (overlays buffers)
    if (qb_full) {
        const float* qb = qb_full + b * 1536;
#pragma unroll
        for (int mi = 0; mi < 6; ++mi)
#pragma unroll
            for (int ni = 0; ni < 4; ++ni) {
                int n  = wn * 64 + ni * 16 + t_l;
                int mb = wm * 96 + mi * 16 + g * 4;
                int byte_off = n * 512 + (((mb >> 6) * 8 + (((mb >> 3) & 7) ^ (n & 7))) * 16) + (mb & 7) * 2;
                f16x4 hv;
#pragma unroll
                for (int r2 = 0; r2 < 4; ++r2) {
                    int row = mb + r2;
                    hv[r2] = (f16)(acc[mi][ni][r2] + qb[(row >> 6) * 512 + h * 64 + (row & 63)]);
                }
                *(f16x4*)(smem + byte_off) = hv;
            }
    } else {
#pragma unroll
        for (int mi = 0; mi < 6; ++mi)
#pragma unroll
            for (int ni = 0; ni < 4; ++ni) {
                int n  = wn * 64 + ni * 16 + t_l;
                int mb = wm * 96 + mi * 16 + g * 4;
                int byte_off = n * 512 + (((mb >> 6) * 8 + (((mb >> 3) & 7) ^ (n & 7))) * 16) + (mb & 7) * 2;
                f16x4 hv;
#pragma unroll
                for (int r2 = 0; r2 < 4; ++r2) {
                    int row = mb + r2;
                    int reg = row >> 6;
                    float qb = qkv_b[reg * 512 + h * 64 + (row & 63)];
                    if (reg == 1) qb *= 0.125f;
                    hv[r2] = (f16)(acc[mi][ni][r2] + qb);
                }
                *(f16x4*)(smem + byte_off) = hv;
            }
    }
    __syncthreads();

    // ---- attention: wave w handles xx = 2w, 2w+1 (16 x's over 8 waves) ----
#pragma unroll
    for (int xc = 0; xc < 2; ++xc) {
        const int xx = w * 2 + xc;
        const int nb = xx * 16;
        const int nrow = nb + t_l;
        const int rbase = nrow * 512;
        const int sw = nrow & 7;

        // QK^T
        f32x4 s_acc = {0.f, 0.f, 0.f, 0.f};
#pragma unroll
        for (int half = 0; half < 2; ++half) {
            int qiA = (g + 4 * half) & 7;
            f16x8 afr = *(const f16x8*)(smem + rbase + ((8 + (qiA ^ sw)) * 16));
            f16x8 bfr = *(const f16x8*)(smem + rbase + ((qiA ^ sw) * 16));
            s_acc = __builtin_amdgcn_mfma_f32_16x16x32_f16(afr, bfr, s_acc, 0, 0, 0);
        }
        // softmax (wave-parallel)
        float sv[4];
#pragma unroll
        for (int r2 = 0; r2 < 4; ++r2)
            sv[r2] = s_acc[r2] + pos_emb[h * 32 + t_l - (g * 4 + r2) + 15];
        float mx = fmaxf(fmaxf(sv[0], sv[1]), fmaxf(sv[2], sv[3]));
        mx = fmaxf(mx, __shfl_xor(mx, 16));
        mx = fmaxf(mx, __shfl_xor(mx, 32));
        float es[4], ssum = 0.f;
#pragma unroll
        for (int r2 = 0; r2 < 4; ++r2) { es[r2] = __expf(sv[r2] - mx); ssum += es[r2]; }
        ssum += __shfl_xor(ssum, 16);
        ssum += __shfl_xor(ssum, 32);
        const float inv = 1.0f / ssum;
        f16x4 pfrag;
#pragma unroll
        for (int r2 = 0; r2 < 4; ++r2) pfrag[r2] = (f16)(es[r2] * inv);

        // PV
        f32x4 o_acc[4];
#pragma unroll
        for (int cb = 0; cb < 4; ++cb) {
            int mV = 128 + cb * 16 + t_l;
            int qiV = (mV >> 3) & 7;
            f16x4 vfrag;
#pragma unroll
            for (int jj2 = 0; jj2 < 4; ++jj2) {
                int nV = nb + g * 4 + jj2;
                vfrag[jj2] = *(const f16*)(smem + nV * 512 + ((16 + (qiV ^ (nV & 7))) * 16) + (mV & 7) * 2);
            }
            f32x4 z = {0.f, 0.f, 0.f, 0.f};
            o_acc[cb] = __builtin_amdgcn_mfma_f32_16x16x16f16(vfrag, pfrag, z, 0, 0, 0);
        }
        // direct f16 store to attnT (full 128B sector per row)
        f16* dst = aT + (((size_t)(b * 2048 + x0 + xx) * 16) + t_l) * 512 + h * 64;
#pragma unroll
        for (int cb = 0; cb < 4; ++cb) {
            f16x4 hv;
#pragma unroll
            for (int r2 = 0; r2 < 4; ++r2) hv[r2] = (f16)o_acc[cb][r2];
            *(f16x4*)(dst + cb * 16 + g * 4) = hv;
        }
    }
}

// ---- k4x: proj GEMM from f16 attnT (R10 proven: oc = XCD) ----
__global__ __launch_bounds__(256) void k4x(const f16* __restrict__ attnT,
                                           const f16* __restrict__ p16,
                                           const float* __restrict__ pb,
                                           float* __restrict__ out) {
    extern __shared__ __attribute__((aligned(16))) char smem[];
    const int oc  = blockIdx.x;        // 0..7 = XCD
    const int win = blockIdx.y;        // 0..127
    const int b   = blockIdx.z;
    const int tid = threadIdx.x;
    const int lane = tid & 63, w = tid >> 6;
    const int t_l = lane & 15, g = lane >> 4;
    const int l8 = lane >> 3;
    const int gc = (lane & 7) ^ l8;

    const f16* Bb = attnT + ((size_t)b * 2048 + win * 16) * 16 * 512;
    const f16* Ab = p16 + (size_t)oc * 64 * 512;

    f32x4 acc[4][4];
#pragma unroll
    for (int mi = 0; mi < 4; ++mi)
#pragma unroll
        for (int ni = 0; ni < 4; ++ni) acc[mi][ni] = (f32x4){0.f, 0.f, 0.f, 0.f};

    {
#pragma unroll
        for (int i = 0; i < 2; ++i) {
            int m0 = w * 16 + i * 8;
            load_lds16(Ab + (size_t)(m0 + l8) * 512 + gc * 8, smem + m0 * 128);
        }
#pragma unroll
        for (int i = 0; i < 8; ++i) {
            int n0 = w * 64 + i * 8;
            load_lds16(Bb + (size_t)(n0 + l8) * 512 + gc * 8, smem + 8192 + n0 * 128);
        }
    }
    __syncthreads();

    int cur = 0;
    for (int ks = 0; ks < 8; ++ks) {
        if (ks < 7) {
            char* bufn = smem + (cur ^ 1) * 40960;
            const int kon = (ks + 1) * 64;
#pragma unroll
            for (int i = 0; i < 2; ++i) {
                int m0 = w * 16 + i * 8;
                load_lds16(Ab + (size_t)(m0 + l8) * 512 + kon + gc * 8, bufn + m0 * 128);
            }
#pragma unroll
            for (int i = 0; i < 8; ++i) {
                int n0 = w * 64 + i * 8;
                load_lds16(Bb + (size_t)(n0 + l8) * 512 + kon + gc * 8, bufn + 8192 + n0 * 128);
            }
        }
        const char* bufc = smem + cur * 40960;
        const f16* a_s = (const f16*)bufc;
        const f16* b_s = (const f16*)(bufc + 8192);
#pragma unroll
        for (int kk = 0; kk < 2; ++kk) {
            const int kb = kk * 4 + g;
            f16x8 af[4], bf[4];
#pragma unroll
            for (int mi = 0; mi < 4; ++mi) {
                int m = mi * 16 + t_l;
                af[mi] = *(const f16x8*)(a_s + m * 64 + ((kb ^ (m & 7)) * 8));
            }
#pragma unroll
            for (int ni = 0; ni < 4; ++ni) {
                int n = w * 64 + ni * 16 + t_l;
                bf[ni] = *(const f16x8*)(b_s + n * 64 + ((kb ^ (n & 7)) * 8));
            }
#pragma unroll
            for (int mi = 0; mi < 4; ++mi)
#pragma unroll
                for (int ni = 0; ni < 4; ++ni)
                    acc[mi][ni] = __builtin_amdgcn_mfma_f32_16x16x32_f16(af[mi], bf[ni], acc[mi][ni], 0, 0, 0);
        }
        __syncthreads();
        cur ^= 1;
    }

    float* y_s = (float*)smem;
#pragma unroll
    for (int mi = 0; mi < 4; ++mi)
#pragma unroll
        for (int ni = 0; ni < 4; ++ni) {
            int nn = w * 64 + ni * 16 + t_l;
            int xx = nn >> 4, tt = nn & 15;
            int ob = mi * 16 + g * 4;
#pragma unroll
            for (int r2 = 0; r2 < 4; ++r2)
                y_s[(ob + r2) * 273 + xx * 17 + tt] = acc[mi][ni][r2];
        }
    __syncthreads();
#pragma unroll
    for (int k = 0; k < 4; ++k) {
        int pair = k * 256 + tid;          // 0..1023
        int o = pair >> 4, t = pair & 15;
        float bias = pb[oc * 64 + o];
        float v[16];
#pragma unroll
        for (int xx = 0; xx < 16; ++xx) v[xx] = y_s[o * 273 + xx * 17 + t] + bias;
        size_t addr = (((size_t)b * 512 + oc * 64 + o) * 16 + t) * 2048 + win * 16;
#pragma unroll
        for (int v4 = 0; v4 < 4; ++v4) {
            float4 ov = {v[v4 * 4 + 0], v[v4 * 4 + 1], v[v4 * 4 + 2], v[v4 * 4 + 3]};
            *(float4*)(out + addr + v4 * 4) = ov;
        }
    }
}

// ================= FALLBACK PATH (fp32, proven) =================

__global__ __launch_bounds__(256) void k_qkv_attn(const float* __restrict__ x,
                                                  const float* __restrict__ qkv_w,
                                                  const float* __restrict__ sc,
                                                  const float* __restrict__ qbias,
                                                  const float* __restrict__ pos_emb,
                                                  float* __restrict__ out) {
    const int h  = blockIdx.x;
    const int x0 = blockIdx.y * 4;
    const int b  = blockIdx.z;
    const int tid = threadIdx.x;

    __shared__ float a_s[192][68];
    __shared__ float b_s[64][68];
    __shared__ float w_s[4][16][17];

    const int ty = tid >> 3;
    const int tx = tid & 7;

    float acc[6][8];
#pragma unroll
    for (int j = 0; j < 6; ++j)
#pragma unroll
        for (int k = 0; k < 8; ++k) acc[j][k] = 0.f;

    for (int ko = 0; ko < 512; ko += 64) {
        __syncthreads();
#pragma unroll
        for (int it = 0; it < 12; ++it) {
            int idx = it * 256 + tid;
            int m = idx >> 4;
            int c4 = (idx & 15) * 4;
            int g = m >> 6, i = m & 63;
            int o = g * 512 + h * 64 + i;
            float4 w4 = *(const float4*)(qkv_w + (size_t)o * 512 + ko + c4);
            float4 s4 = *(const float4*)(sc + b * 512 + ko + c4);
            float ksc = (g == 1) ? 0.125f : 1.0f;
            float4 v;
            v.x = w4.x * s4.x * ksc; v.y = w4.y * s4.y * ksc;
            v.z = w4.z * s4.z * ksc; v.w = w4.w * s4.w * ksc;
            *(float4*)&a_s[m][c4] = v;
        }
#pragma unroll
        for (int it = 0; it < 4; ++it) {
            int idx = it * 256 + tid;
            int cc = idx >> 4, t = idx & 15;
            float4 v = *(const float4*)(x + ((size_t)((b * 512 + ko + cc) * 16 + t)) * 2048 + x0);
            *(float4*)&b_s[cc][t * 4] = v;
        }
        __syncthreads();
#pragma unroll 4
        for (int cc = 0; cc < 64; ++cc) {
            float av[6];
#pragma unroll
            for (int j = 0; j < 6; ++j) av[j] = a_s[ty * 6 + j][cc];
            float4 b0 = *(const float4*)&b_s[cc][tx * 8];
            float4 b1 = *(const float4*)&b_s[cc][tx * 8 + 4];
            float bv[8] = {b0.x, b0.y, b0.z, b0.w, b1.x, b1.y, b1.z, b1.w};
#pragma unroll
            for (int j = 0; j < 6; ++j)
#pragma unroll
                for (int k = 0; k < 8; ++k)
                    acc[j][k] = fmaf(av[j], bv[k], acc[j][k]);
        }
    }
#pragma unroll
    for (int j = 0; j < 6; ++j) {
        int m = ty * 6 + j;
        int o = (m >> 6) * 512 + h * 64 + (m & 63);
        float qb = qbias[b * 1536 + o];
#pragma unroll
        for (int k = 0; k < 8; ++k) acc[j][k] += qb;
    }
    __syncthreads();
#pragma unroll
    for (int j = 0; j < 6; ++j)
#pragma unroll
        for (int k = 0; k < 8; ++k)
            a_s[ty * 6 + j][tx * 8 + k] = acc[j][k];
    __syncthreads();

    {
        const int xx = tid >> 6;
        const int t  = (tid >> 2) & 15;
        const int uq = tid & 3;
        float l[4] = {0.f, 0.f, 0.f, 0.f};
        for (int i = 0; i < 64; ++i) {
            float qv = a_s[i][t * 4 + xx];
#pragma unroll
            for (int uu = 0; uu < 4; ++uu)
                l[uu] = fmaf(qv, a_s[64 + i][(uq * 4 + uu) * 4 + xx], l[uu]);
        }
#pragma unroll
        for (int uu = 0; uu < 4; ++uu) {
            int u = uq * 4 + uu;
            w_s[xx][t][u] = l[uu] + pos_emb[h * 32 + t - u + 15];
        }
    }
    __syncthreads();
    if (tid < 64) {
        const int xx = tid >> 4, t = tid & 15;
        float mx = -3.4e38f;
#pragma unroll
        for (int u = 0; u < 16; ++u) mx = fmaxf(mx, w_s[xx][t][u]);
        float ssum = 0.f;
#pragma unroll
        for (int u = 0; u < 16; ++u) {
            float e = __expf(w_s[xx][t][u] - mx);
            w_s[xx][t][u] = e;
            ssum += e;
        }
        float inv = 1.0f / ssum;
#pragma unroll
        for (int u = 0; u < 16; ++u) w_s[xx][t][u] *= inv;
    }
    __syncthreads();
    {
        const int i  = tid & 63;
        const int t4 = tid >> 6;
        float4 varr[16];
#pragma unroll
        for (int u = 0; u < 16; ++u) varr[u] = *(const float4*)&a_s[128 + i][u * 4];
#pragma unroll
        for (int tt = 0; tt < 4; ++tt) {
            int t = t4 * 4 + tt;
            float4 o4 = {0.f, 0.f, 0.f, 0.f};
#pragma unroll
            for (int u = 0; u < 16; ++u) {
                o4.x = fmaf(w_s[0][t][u], varr[u].x, o4.x);
                o4.y = fmaf(w_s[1][t][u], varr[u].y, o4.y);
                o4.z = fmaf(w_s[2][t][u], varr[u].z, o4.z);
                o4.w = fmaf(w_s[3][t][u], varr[u].w, o4.w);
            }
            *(float4*)(out + ((size_t)((b * 512 + h * 64 + i) * 16 + t)) * 2048 + x0) = o4;
        }
    }
}

__global__ __launch_bounds__(256) void k_proj(const float* __restrict__ pw,
                                              const float* __restrict__ pb,
                                              float* __restrict__ io) {
    const int n0 = blockIdx.x * 32;
    const int b  = blockIdx.y;
    const int tid = threadIdx.x;
    __shared__ float in_s[512][36];
    __shared__ float w_s[128][65];

    {
        const float* src = io + (size_t)b * 512 * 32768 + n0;
#pragma unroll
        for (int it = 0; it < 64; ++it) {
            int idx = it * 256 + tid;
            int r = idx >> 5, j = idx & 31;
            in_s[r][j] = src[(size_t)r * 32768 + j];
        }
    }
    __syncthreads();

    const int ty = tid >> 3;
    const int tx = tid & 7;

    for (int mo = 0; mo < 512; mo += 128) {
        float acc[4][4];
#pragma unroll
        for (int j = 0; j < 4; ++j)
#pragma unroll
            for (int k = 0; k < 4; ++k) acc[j][k] = 0.f;

        for (int ko = 0; ko < 512; ko += 64) {
#pragma unroll
            for (int it = 0; it < 32; ++it) {
                int idx = it * 256 + tid;
                int m = idx >> 6, cc = idx & 63;
                w_s[m][cc] = pw[(size_t)(mo + m) * 512 + ko + cc];
            }
            __syncthreads();
#pragma unroll 4
            for (int cc = 0; cc < 64; ++cc) {
                float4 bv = *(const float4*)&in_s[ko + cc][tx * 4];
                float a0 = w_s[ty * 4 + 0][cc];
                float a1 = w_s[ty * 4 + 1][cc];
                float a2 = w_s[ty * 4 + 2][cc];
                float a3 = w_s[ty * 4 + 3][cc];
                acc[0][0] = fmaf(a0, bv.x, acc[0][0]); acc[0][1] = fmaf(a0, bv.y, acc[0][1]);
                acc[0][2] = fmaf(a0, bv.z, acc[0][2]); acc[0][3] = fmaf(a0, bv.w, acc[0][3]);
                acc[1][0] = fmaf(a1, bv.x, acc[1][0]); acc[1][1] = fmaf(a1, bv.y, acc[1][1]);
                acc[1][2] = fmaf(a1, bv.z, acc[1][2]); acc[1][3] = fmaf(a1, bv.w, acc[1][3]);
                acc[2][0] = fmaf(a2, bv.x, acc[2][0]); acc[2][1] = fmaf(a2, bv.y, acc[2][1]);
                acc[2][2] = fmaf(a2, bv.z, acc[2][2]); acc[2][3] = fmaf(a2, bv.w, acc[2][3]);
                acc[3][0] = fmaf(a3, bv.x, acc[3][0]); acc[3][1] = fmaf(a3, bv.y, acc[3][1]);
                acc[3][2] = fmaf(a3, bv.z, acc[3][2]); acc[3][3] = fmaf(a3, bv.w, acc[3][3]);
            }
            __syncthreads();
        }
#pragma unroll
        for (int j = 0; j < 4; ++j) {
            int m = mo + ty * 4 + j;
            float bias = pb[m];
            float4 o4 = {acc[j][0] + bias, acc[j][1] + bias, acc[j][2] + bias, acc[j][3] + bias};
            *(float4*)(io + (size_t)(b * 512 + m) * 32768 + n0 + tx * 4) = o4;
        }
    }
}

extern "C" void kernel_launch(void* const* d_in, const int* in_sizes, int n_in,
                              void* d_out, int out_size, void* d_ws, size_t ws_size,
                              hipStream_t stream) {
    (void)in_sizes; (void)n_in; (void)out_size;
    const float* x       = (const float*)d_in[0];
    const float* gn_w    = (const float*)d_in[1];
    const float* gn_b    = (const float*)d_in[2];
    const float* qkv_w   = (const float*)d_in[3];
    const float* qkv_b   = (const float*)d_in[4];
    const float* proj_w  = (const float*)d_in[5];
    const float* proj_b  = (const float*)d_in[6];
    const float* pos_emb = (const float*)d_in[7];
    float* out = (float*)d_out;

    float* ws    = (float*)d_ws;
    float* psum  = ws;            // 2048 (T2/T3)
    float* psq   = ws + 2048;     // 2048
    float* mu    = ws + 4096;     // 128
    float* rs    = ws + 4224;     // 128
    float* sc    = ws + 4352;     // 2048
    float* beta  = ws + 6400;     // 2048
    float* qbias = ws + 8448;     // 6144

    const size_t XT_BYTES = (size_t)4 * 2048 * 16 * 512 * 2;   // 134.2 MB

    // T1 layout
    const size_t W16B_OFF = 65536;
    const size_t P16B_OFF = W16B_OFF + (size_t)4 * 1536 * 512 * 2;
    const size_t XT1_OFF  = P16B_OFF + (size_t)512 * 512 * 2;
    const size_t AT1_OFF  = XT1_OFF + XT_BYTES;
    const size_t NEED_T1  = AT1_OFF + XT_BYTES;

    // T2 layout
    const size_t W16_OFF = 65536;
    const size_t P16_OFF = W16_OFF + (size_t)1536 * 512 * 2;
    const size_t XT2_OFF = P16_OFF + (size_t)512 * 512 * 2;
    const size_t AT2_OFF = XT2_OFF + XT_BYTES;
    const size_t NEED_T2 = AT2_OFF + XT_BYTES;

    const int K3_LDS = 131072;
    const int K4_LDS = 81920;
    hipError_t a1 = hipFuncSetAttribute((const void*)k3_mfma,
                                        hipFuncAttributeMaxDynamicSharedMemorySize, K3_LDS);
    hipError_t a2 = hipFuncSetAttribute((const void*)k4x,
                                        hipFuncAttributeMaxDynamicSharedMemorySize, K4_LDS);

    if (ws_size >= NEED_T1 && a1 == hipSuccess && a2 == hipSuccess) {
        f16* w16b  = (f16*)((char*)d_ws + W16B_OFF);
        f16* p16   = (f16*)((char*)d_ws + P16B_OFF);
        f16* xT    = (f16*)((char*)d_ws + XT1_OFF);
        f16* attnT = (f16*)((char*)d_ws + AT1_OFF);
        float* psum2 = (float*)((char*)d_ws + AT1_OFF);            // overlay (pre-k3 lifetime)
        float* psq2  = (float*)((char*)d_ws + AT1_OFF + 262144);
        k_xtstat<<<dim3(32, 8, 64), dim3(256), 0, stream>>>(x, xT, psum2, psq2);
        k_gn_final2<<<dim3(1), dim3(128), 0, stream>>>(psum2, psq2, mu, rs);
        k_fold_sc<<<dim3(8), dim3(256), 0, stream>>>(gn_w, gn_b, mu, rs, sc, beta);
        k_fold_bias<<<dim3(24), dim3(256), 0, stream>>>(qkv_w, qkv_b, beta, qbias);
        k_prep_wb<<<dim3(768, 4), dim3(256), 0, stream>>>(qkv_w, sc, w16b);
        k_prep_p<<<dim3(256), dim3(256), 0, stream>>>(proj_w, p16);
        k3_mfma<<<dim3(8, 128, 4), dim3(512), K3_LDS, stream>>>(xT, w16b, (size_t)786432,
                                                                qkv_b, qbias, pos_emb, attnT);
        k4x<<<dim3(8, 128, 4), dim3(256), K4_LDS, stream>>>(attnT, p16, proj_b, out);
    } else if (ws_size >= NEED_T2 && a1 == hipSuccess && a2 == hipSuccess) {
        f16* w16   = (f16*)((char*)d_ws + W16_OFF);
        f16* p16   = (f16*)((char*)d_ws + P16_OFF);
        f16* xT    = (f16*)((char*)d_ws + XT2_OFF);
        f16* attnT = (f16*)((char*)d_ws + AT2_OFF);
        k_gn_part<<<dim3(2048), dim3(256), 0, stream>>>(x, psum, psq);
        k_gn_final<<<dim3(1), dim3(128), 0, stream>>>(psum, psq, mu, rs);
        k_fold_sc<<<dim3(8), dim3(256), 0, stream>>>(gn_w, gn_b, mu, rs, sc, beta);
        k_prep_w<<<dim3(1024), dim3(256), 0, stream>>>(qkv_w, proj_w, w16, p16);
        k_xt<<<dim3(32, 8, 64), dim3(256), 0, stream>>>(x, sc, beta, xT);
        k3_mfma<<<dim3(8, 128, 4), dim3(512), K3_LDS, stream>>>(xT, w16, (size_t)0,
                                                                qkv_b, nullptr, pos_emb, attnT);
        k4x<<<dim3(8, 128, 4), dim3(256), K4_LDS, stream>>>(attnT, p16, proj_b, out);
    } else {
        k_gn_part<<<dim3(2048), dim3(256), 0, stream>>>(x, psum, psq);
        k_gn_final<<<dim3(1), dim3(128), 0, stream>>>(psum, psq, mu, rs);
        k_fold_sc<<<dim3(8), dim3(256), 0, stream>>>(gn_w, gn_b, mu, rs, sc, beta);
        k_fold_bias<<<dim3(24), dim3(256), 0, stream>>>(qkv_w, qkv_b, beta, qbias);
        k_qkv_attn<<<dim3(8, 512, 4), dim3(256), 0, stream>>>(x, qkv_w, sc, qbias, pos_emb, out);
        k_proj<<<dim3(1024, 4), dim3(256), 0, stream>>>(proj_w, proj_b, out);
    }
}

// Round 15
// 600.493 us; speedup vs baseline: 1.0451x; 1.0451x over previous
//
#include <hip/hip_runtime.h>
#include <math.h>

#define EPSV 1e-5f

typedef _Float16 f16;
typedef _Float16 f16x8 __attribute__((ext_vector_type(8)));
typedef _Float16 f16x4 __attribute__((ext_vector_type(4)));
typedef float f32x4 __attribute__((ext_vector_type(4)));

typedef const __attribute__((address_space(1))) void* as1_cvp;
typedef __attribute__((address_space(3))) void* as3_vp;
__device__ __forceinline__ void load_lds16(const void* g, void* l) {
    __builtin_amdgcn_global_load_lds((as1_cvp)g, (as3_vp)l, 16, 0, 0);
}

static constexpr int GROUP_N = 16 * 16 * 2048;   // elems per (b,g) group

// ---------------- T1: fused stats + raw-f16 transpose ----------------
__global__ __launch_bounds__(256) void k_xtstat(const float* __restrict__ x,
                                                f16* __restrict__ xT,
                                                float* __restrict__ psum2,
                                                float* __restrict__ psq2) {
    const int x0 = blockIdx.x * 64;
    const int c0 = blockIdx.y * 64;
    const int b  = blockIdx.z >> 4, t = blockIdx.z & 15;
    const int tid = threadIdx.x;
    __shared__ float tile[64][68];
#pragma unroll
    for (int it = 0; it < 4; ++it) {
        int idx = it * 256 + tid;            // 0..1023
        int c = idx >> 4, xq = idx & 15;
        float4 v = *(const float4*)(x + (((size_t)(b * 512 + c0 + c) * 16 + t) * 2048) + x0 + xq * 4);
        tile[c][xq * 4 + 0] = v.x;
        tile[c][xq * 4 + 1] = v.y;
        tile[c][xq * 4 + 2] = v.z;
        tile[c][xq * 4 + 3] = v.w;
    }
    __syncthreads();
#pragma unroll
    for (int it = 0; it < 2; ++it) {
        int idx = it * 256 + tid;            // 0..511
        int xr = idx >> 3, ch = idx & 7;
        f16x8 h;
#pragma unroll
        for (int e = 0; e < 8; ++e) h[e] = (f16)tile[ch * 8 + e][xr];
        *(f16x8*)(xT + (((size_t)(b * 2048 + x0 + xr) * 16 + t) * 512) + c0 + ch * 8) = h;
    }
    {
        const int gg = tid >> 6, lane = tid & 63;
        float s = 0.f, q = 0.f;
#pragma unroll
        for (int i = 0; i < 16; ++i) {
            float v = tile[gg * 16 + i][lane];
            s += v; q += v * v;
        }
#pragma unroll
        for (int off = 32; off > 0; off >>= 1) {
            s += __shfl_down(s, off);
            q += __shfl_down(q, off);
        }
        if (lane == 0) {
            int grp = b * 32 + blockIdx.y * 4 + gg;
            int col = blockIdx.x * 16 + t;
            psum2[grp * 512 + col] = s;
            psq2[grp * 512 + col] = q;
        }
    }
}

__global__ void k_gn_final2(const float* __restrict__ psum2, const float* __restrict__ psq2,
                            float* __restrict__ mu, float* __restrict__ rs) {
    const int t = threadIdx.x;  // 0..127
    float s = 0.f, q = 0.f;
    const float* ps = psum2 + t * 512;
    const float* pq = psq2 + t * 512;
#pragma unroll 4
    for (int i = 0; i < 512; i += 4) {
        float4 a = *(const float4*)(ps + i);
        float4 c = *(const float4*)(pq + i);
        s += a.x + a.y + a.z + a.w;
        q += c.x + c.y + c.z + c.w;
    }
    const float m = s / (float)GROUP_N;
    float v = q / (float)GROUP_N - m * m;
    mu[t] = m;
    rs[t] = 1.0f / sqrtf(v + EPSV);
}

// ---------------- T2/T3 stats ----------------
__global__ __launch_bounds__(256) void k_gn_part(const float* __restrict__ x,
                                                 float* __restrict__ psum,
                                                 float* __restrict__ psq) {
    const int blk = blockIdx.x;
    const int tid = threadIdx.x;
    const float* p = x + (size_t)blk * 32768;
    float s = 0.f, q = 0.f;
#pragma unroll
    for (int i = 0; i < 32; ++i) {
        float4 v = *(const float4*)(p + (size_t)(i * 256 + tid) * 4);
        s += v.x + v.y + v.z + v.w;
        q += v.x * v.x + v.y * v.y + v.z * v.z + v.w * v.w;
    }
#pragma unroll
    for (int off = 32; off > 0; off >>= 1) {
        s += __shfl_down(s, off);
        q += __shfl_down(q, off);
    }
    __shared__ float ls[4], lq[4];
    const int wave = tid >> 6, lane = tid & 63;
    if (lane == 0) { ls[wave] = s; lq[wave] = q; }
    __syncthreads();
    if (tid == 0) {
        psum[blk] = ls[0] + ls[1] + ls[2] + ls[3];
        psq[blk]  = lq[0] + lq[1] + lq[2] + lq[3];
    }
}

__global__ void k_gn_final(const float* __restrict__ psum, const float* __restrict__ psq,
                           float* __restrict__ mu, float* __restrict__ rs) {
    const int t = threadIdx.x;  // 0..127
    float s = 0.f, q = 0.f;
#pragma unroll
    for (int i = 0; i < 16; ++i) { s += psum[t * 16 + i]; q += psq[t * 16 + i]; }
    const float m = s / (float)GROUP_N;
    float v = q / (float)GROUP_N - m * m;
    mu[t] = m;
    rs[t] = 1.0f / sqrtf(v + EPSV);
}

__global__ __launch_bounds__(256) void k_fold_sc(const float* __restrict__ gn_w,
                                                 const float* __restrict__ gn_b,
                                                 const float* __restrict__ mu,
                                                 const float* __restrict__ rs,
                                                 float* __restrict__ sc,
                                                 float* __restrict__ beta) {
    const int u = blockIdx.x * 256 + threadIdx.x;  // 0..2047
    const int b = u >> 9, c = u & 511;
    const int g = c >> 4;
    const float r = rs[b * 32 + g], m = mu[b * 32 + g];
    const float s = r * gn_w[c];
    sc[u]   = s;
    beta[u] = gn_b[c] - m * s;
}

__global__ __launch_bounds__(256) void k_fold_bias(const float* __restrict__ qkv_w,
                                                   const float* __restrict__ qkv_b,
                                                   const float* __restrict__ beta,
                                                   float* __restrict__ qbias) {
    const int u = blockIdx.x * 256 + threadIdx.x;  // 0..6143
    const int b = u / 1536, o = u % 1536;
    float acc = qkv_b[o];
    const float* wr = qkv_w + (size_t)o * 512;
    const float* be = beta + b * 512;
#pragma unroll 4
    for (int c = 0; c < 512; c += 4) {
        float4 w4 = *(const float4*)(wr + c);
        float4 b4 = *(const float4*)(be + c);
        acc += w4.x * b4.x + w4.y * b4.y + w4.z * b4.z + w4.w * b4.w;
    }
    if (o >= 512 && o < 1024) acc *= 0.125f;
    qbias[u] = acc;
}

__global__ __launch_bounds__(256) void k_prep_wb(const float* __restrict__ qkv_w,
                                                 const float* __restrict__ sc,
                                                 f16* __restrict__ w16b) {
    const int id = blockIdx.x * 256 + threadIdx.x;  // 0..196607
    const int b  = blockIdx.y;
    const int e0 = id * 4;
    const int o  = e0 >> 9;
    const float ksc = (o >= 512 && o < 1024) ? 0.125f : 1.0f;
    float4 wv = *(const float4*)(qkv_w + e0);
    float4 s4 = *(const float4*)(sc + b * 512 + (e0 & 511));
    f16x4 h = { (f16)(wv.x * s4.x * ksc), (f16)(wv.y * s4.y * ksc),
                (f16)(wv.z * s4.z * ksc), (f16)(wv.w * s4.w * ksc) };
    *(f16x4*)(w16b + (size_t)b * 786432 + e0) = h;
}

__global__ __launch_bounds__(256) void k_prep_p(const float* __restrict__ proj_w,
                                                f16* __restrict__ p16) {
    const int id = blockIdx.x * 256 + threadIdx.x;  // 0..65535
    const int e0 = id * 4;
    float4 v = *(const float4*)(proj_w + e0);
    f16x4 h = { (f16)v.x, (f16)v.y, (f16)v.z, (f16)v.w };
    *(f16x4*)(p16 + e0) = h;
}

__global__ __launch_bounds__(256) void k_prep_w(const float* __restrict__ qkv_w,
                                                const float* __restrict__ proj_w,
                                                f16* __restrict__ w16,
                                                f16* __restrict__ p16) {
    const int id = blockIdx.x * 256 + threadIdx.x;  // 0..262143
    if (id < 196608) {
        const int e0 = id * 4;
        const int o  = e0 >> 9;
        const float ksc = (o >= 512 && o < 1024) ? 0.125f : 1.0f;
        float4 v = *(const float4*)(qkv_w + e0);
        f16x4 h = { (f16)(v.x * ksc), (f16)(v.y * ksc), (f16)(v.z * ksc), (f16)(v.w * ksc) };
        *(f16x4*)(w16 + e0) = h;
    } else {
        const int e0 = (id - 196608) * 4;
        float4 v = *(const float4*)(proj_w + e0);
        f16x4 h = { (f16)v.x, (f16)v.y, (f16)v.z, (f16)v.w };
        *(f16x4*)(p16 + e0) = h;
    }
}

__global__ __launch_bounds__(256) void k_xt(const float* __restrict__ x,
                                            const float* __restrict__ sc,
                                            const float* __restrict__ beta,
                                            f16* __restrict__ xT) {
    const int x0 = blockIdx.x * 64;
    const int c0 = blockIdx.y * 64;
    const int b  = blockIdx.z >> 4, t = blockIdx.z & 15;
    const int tid = threadIdx.x;
    __shared__ float tile[64][68];
#pragma unroll
    for (int it = 0; it < 4; ++it) {
        int idx = it * 256 + tid;            // 0..1023
        int c = idx >> 4, xq = idx & 15;
        int cg = c0 + c;
        float s = sc[b * 512 + cg], be = beta[b * 512 + cg];
        float4 v = *(const float4*)(x + (((size_t)(b * 512 + cg) * 16 + t) * 2048) + x0 + xq * 4);
        tile[c][xq * 4 + 0] = v.x * s + be;
        tile[c][xq * 4 + 1] = v.y * s + be;
        tile[c][xq * 4 + 2] = v.z * s + be;
        tile[c][xq * 4 + 3] = v.w * s + be;
    }
    __syncthreads();
#pragma unroll
    for (int it = 0; it < 2; ++it) {
        int idx = it * 256 + tid;            // 0..511
        int xr = idx >> 3, ch = idx & 7;
        f16x8 h;
#pragma unroll
        for (int e = 0; e < 8; ++e) h[e] = (f16)tile[ch * 8 + e][xr];
        *(f16x8*)(xT + (((size_t)(b * 2048 + x0 + xr) * 16 + t) * 512) + c0 + ch * 8) = h;
    }
}

// ---- k3_mfma: fused QKV GEMM + MFMA attention (R13 proven geometry + T5) ----
// Grid dim3(8,256,4), 256 thr, 2 blocks/CU: h = XCD, gload_lds dbuf,
// 1 barrier/k-step. T5 s_setprio(1) around the MFMA cluster: 2 desynced
// blocks/CU give wave-phase diversity for the CU scheduler to exploit.
__global__ __launch_bounds__(256) void k3_mfma(const f16* __restrict__ xT,
                                               const f16* __restrict__ wsrc,
                                               size_t w_bstride,
                                               const float* __restrict__ qkv_b,
                                               const float* __restrict__ qb_full,
                                               const float* __restrict__ pos_emb,
                                               float* __restrict__ out,
                                               f16* __restrict__ aT) {
    extern __shared__ __attribute__((aligned(16))) char smem[];
    const int h  = blockIdx.x;
    const int x0 = blockIdx.y * 8;
    const int b  = blockIdx.z;
    const int tid = threadIdx.x;
    const int lane = tid & 63, w = tid >> 6;
    const int wm = w >> 1, wn = w & 1;
    const int t_l = lane & 15, g = lane >> 4;

    const f16* xTb = xT + ((size_t)b * 2048 + x0) * 16 * 512;
    const f16* Wb  = wsrc + (size_t)b * w_bstride;

    const int l8 = lane >> 3;            // 0..7
    const int gc = (lane & 7) ^ l8;      // pre-swizzled global chunk

    f32x4 acc[6][4];
#pragma unroll
    for (int mi = 0; mi < 6; ++mi)
#pragma unroll
        for (int ni = 0; ni < 4; ++ni) acc[mi][ni] = (f32x4){0.f, 0.f, 0.f, 0.f};

    // stage tile 0 into buffer 0
    {
#pragma unroll
        for (int i = 0; i < 6; ++i) {
            int m0 = (w * 6 + i) * 8;
            int m = m0 + l8;
            int o = (m >> 6) * 512 + h * 64 + (m & 63);
            load_lds16(Wb + (size_t)o * 512 + gc * 8, smem + m0 * 128);
        }
#pragma unroll
        for (int i = 0; i < 4; ++i) {
            int n0 = (w * 4 + i) * 8;
            int n = n0 + l8;
            load_lds16(xTb + (size_t)n * 512 + gc * 8, smem + 24576 + n0 * 128);
        }
    }
    __syncthreads();

    int cur = 0;
    for (int ks = 0; ks < 8; ++ks) {
        if (ks < 7) {
            char* bufn = smem + (cur ^ 1) * 40960;
            const int kon = (ks + 1) * 64;
#pragma unroll
            for (int i = 0; i < 6; ++i) {
                int m0 = (w * 6 + i) * 8;
                int m = m0 + l8;
                int o = (m >> 6) * 512 + h * 64 + (m & 63);
                load_lds16(Wb + (size_t)o * 512 + kon + gc * 8, bufn + m0 * 128);
            }
#pragma unroll
            for (int i = 0; i < 4; ++i) {
                int n0 = (w * 4 + i) * 8;
                int n = n0 + l8;
                load_lds16(xTb + (size_t)n * 512 + kon + gc * 8, bufn + 24576 + n0 * 128);
            }
        }
        const char* bufc = smem + cur * 40960;
        const f16* a_s = (const f16*)bufc;
        const f16* b_s = (const f16*)(bufc + 24576);
        __builtin_amdgcn_s_setprio(1);
#pragma unroll
        for (int kk = 0; kk < 2; ++kk) {
            const int kb = kk * 4 + g;
            f16x8 af[6], bf[4];
#pragma unroll
            for (int mi = 0; mi < 6; ++mi) {
                int m = wm * 96 + mi * 16 + t_l;
                af[mi] = *(const f16x8*)(a_s + m * 64 + ((kb ^ (m & 7)) * 8));
            }
#pragma unroll
            for (int ni = 0; ni < 4; ++ni) {
                int n = wn * 64 + ni * 16 + t_l;
                bf[ni] = *(const f16x8*)(b_s + n * 64 + ((kb ^ (n & 7)) * 8));
            }
#pragma unroll
            for (int mi = 0; mi < 6; ++mi)
#pragma unroll
                for (int ni = 0; ni < 4; ++ni)
                    acc[mi][ni] = __builtin_amdgcn_mfma_f32_16x16x32_f16(af[mi], bf[ni], acc[mi][ni], 0, 0, 0);
        }
        __builtin_amdgcn_s_setprio(0);
        __syncthreads();
        cur ^= 1;
    }

    // epilogue: acc + bias -> qkvT[n][m] f16, swizzled chunks
    if (qb_full) {
        const float* qb = qb_full + b * 1536;
#pragma unroll
        for (int mi = 0; mi < 6; ++mi)
#pragma unroll
            for (int ni = 0; ni < 4; ++ni) {
                int n  = wn * 64 + ni * 16 + t_l;
                int mb = wm * 96 + mi * 16 + g * 4;
                int byte_off = n * 512 + (((mb >> 6) * 8 + (((mb >> 3) & 7) ^ (n & 7))) * 16) + (mb & 7) * 2;
                f16x4 hv;
#pragma unroll
                for (int r2 = 0; r2 < 4; ++r2) {
                    int row = mb + r2;
                    hv[r2] = (f16)(acc[mi][ni][r2] + qb[(row >> 6) * 512 + h * 64 + (row & 63)]);
                }
                *(f16x4*)(smem + byte_off) = hv;
            }
    } else {
#pragma unroll
        for (int mi = 0; mi < 6; ++mi)
#pragma unroll
            for (int ni = 0; ni < 4; ++ni) {
                int n  = wn * 64 + ni * 16 + t_l;
                int mb = wm * 96 + mi * 16 + g * 4;
                int byte_off = n * 512 + (((mb >> 6) * 8 + (((mb >> 3) & 7) ^ (n & 7))) * 16) + (mb & 7) * 2;
                f16x4 hv;
#pragma unroll
                for (int r2 = 0; r2 < 4; ++r2) {
                    int row = mb + r2;
                    int reg = row >> 6;
                    float qb = qkv_b[reg * 512 + h * 64 + (row & 63)];
                    if (reg == 1) qb *= 0.125f;
                    hv[r2] = (f16)(acc[mi][ni][r2] + qb);
                }
                *(f16x4*)(smem + byte_off) = hv;
            }
    }
    __syncthreads();

    // ---- attention: wave w handles xx = 2w, 2w+1 ----
#pragma unroll
    for (int xc = 0; xc < 2; ++xc) {
        const int xx = w * 2 + xc;
        const int nb = xx * 16;
        const int nrow = nb + t_l;
        const int rbase = nrow * 512;
        const int sw = nrow & 7;

        f32x4 s_acc = {0.f, 0.f, 0.f, 0.f};
#pragma unroll
        for (int half = 0; half < 2; ++half) {
            int qiA = (g + 4 * half) & 7;
            f16x8 afr = *(const f16x8*)(smem + rbase + ((8 + (qiA ^ sw)) * 16));
            f16x8 bfr = *(const f16x8*)(smem + rbase + ((qiA ^ sw) * 16));
            s_acc = __builtin_amdgcn_mfma_f32_16x16x32_f16(afr, bfr, s_acc, 0, 0, 0);
        }
        float sv[4];
#pragma unroll
        for (int r2 = 0; r2 < 4; ++r2)
            sv[r2] = s_acc[r2] + pos_emb[h * 32 + t_l - (g * 4 + r2) + 15];
        float mx = fmaxf(fmaxf(sv[0], sv[1]), fmaxf(sv[2], sv[3]));
        mx = fmaxf(mx, __shfl_xor(mx, 16));
        mx = fmaxf(mx, __shfl_xor(mx, 32));
        float es[4], ssum = 0.f;
#pragma unroll
        for (int r2 = 0; r2 < 4; ++r2) { es[r2] = __expf(sv[r2] - mx); ssum += es[r2]; }
        ssum += __shfl_xor(ssum, 16);
        ssum += __shfl_xor(ssum, 32);
        const float inv = 1.0f / ssum;
        f16x4 pfrag;
#pragma unroll
        for (int r2 = 0; r2 < 4; ++r2) pfrag[r2] = (f16)(es[r2] * inv);

        f32x4 o_acc[4];
#pragma unroll
        for (int cb = 0; cb < 4; ++cb) {
            int mV = 128 + cb * 16 + t_l;
            int qiV = (mV >> 3) & 7;
            f16x4 vfrag;
#pragma unroll
            for (int jj2 = 0; jj2 < 4; ++jj2) {
                int nV = nb + g * 4 + jj2;
                vfrag[jj2] = *(const f16*)(smem + nV * 512 + ((16 + (qiV ^ (nV & 7))) * 16) + (mV & 7) * 2);
            }
            f32x4 z = {0.f, 0.f, 0.f, 0.f};
            o_acc[cb] = __builtin_amdgcn_mfma_f32_16x16x16f16(vfrag, pfrag, z, 0, 0, 0);
        }
        if (aT) {
            f16* dst = aT + (((size_t)(b * 2048 + x0 + xx) * 16) + t_l) * 512 + h * 64;
#pragma unroll
            for (int cb = 0; cb < 4; ++cb) {
                f16x4 hv;
#pragma unroll
                for (int r2 = 0; r2 < 4; ++r2) hv[r2] = (f16)o_acc[cb][r2];
                *(f16x4*)(dst + cb * 16 + g * 4) = hv;
            }
        } else {
#pragma unroll
            for (int cb = 0; cb < 4; ++cb) {
                int qd = cb * 4 + g;
                int byte_off = rbase + (((qd >> 3) * 8 + ((qd & 7) ^ sw)) * 16);
                *(f32x4*)(smem + byte_off) = o_acc[cb];
            }
        }
    }
    if (!aT) {
        __syncthreads();
        const int c = tid & 63, tq = tid >> 6;
        const int qc = c >> 2;
#pragma unroll
        for (int ti = 0; ti < 4; ++ti) {
            int t = tq * 4 + ti;
            float vals[8];
#pragma unroll
            for (int xx = 0; xx < 8; ++xx) {
                int n2 = xx * 16 + t;
                vals[xx] = *(const float*)(smem + n2 * 512 + (((qc >> 3) * 8 + ((qc & 7) ^ (n2 & 7))) * 16) + (c & 3) * 4);
            }
            float4 lo = {vals[0], vals[1], vals[2], vals[3]};
            float4 hi = {vals[4], vals[5], vals[6], vals[7]};
            size_t oaddr = (((size_t)b * 512 + h * 64 + c) * 16 + t) * 2048 + x0;
            *(float4*)(out + oaddr) = lo;
            *(float4*)(out + oaddr + 4) = hi;
        }
    }
}

// ---- k4x: proj GEMM from f16 attnT (R10 proven + T5) ----
__global__ __launch_bounds__(256) void k4x(const f16* __restrict__ attnT,
                                           const f16* __restrict__ p16,
                                           const float* __restrict__ pb,
                                           float* __restrict__ out) {
    extern __shared__ __attribute__((aligned(16))) char smem[];
    const int oc  = blockIdx.x;        // 0..7 = XCD
    const int win = blockIdx.y;        // 0..127
    const int b   = blockIdx.z;
    const int tid = threadIdx.x;
    const int lane = tid & 63, w = tid >> 6;
    const int t_l = lane & 15, g = lane >> 4;
    const int l8 = lane >> 3;
    const int gc = (lane & 7) ^ l8;

    const f16* Bb = attnT + ((size_t)b * 2048 + win * 16) * 16 * 512;
    const f16* Ab = p16 + (size_t)oc * 64 * 512;

    f32x4 acc[4][4];
#pragma unroll
    for (int mi = 0; mi < 4; ++mi)
#pragma unroll
        for (int ni = 0; ni < 4; ++ni) acc[mi][ni] = (f32x4){0.f, 0.f, 0.f, 0.f};

    {
#pragma unroll
        for (int i = 0; i < 2; ++i) {
            int m0 = w * 16 + i * 8;
            load_lds16(Ab + (size_t)(m0 + l8) * 512 + gc * 8, smem + m0 * 128);
        }
#pragma unroll
        for (int i = 0; i < 8; ++i) {
            int n0 = w * 64 + i * 8;
            load_lds16(Bb + (size_t)(n0 + l8) * 512 + gc * 8, smem + 8192 + n0 * 128);
        }
    }
    __syncthreads();

    int cur = 0;
    for (int ks = 0; ks < 8; ++ks) {
        if (ks < 7) {
            char* bufn = smem + (cur ^ 1) * 40960;
            const int kon = (ks + 1) * 64;
#pragma unroll
            for (int i = 0; i < 2; ++i) {
                int m0 = w * 16 + i * 8;
                load_lds16(Ab + (size_t)(m0 + l8) * 512 + kon + gc * 8, bufn + m0 * 128);
            }
#pragma unroll
            for (int i = 0; i < 8; ++i) {
                int n0 = w * 64 + i * 8;
                load_lds16(Bb + (size_t)(n0 + l8) * 512 + kon + gc * 8, bufn + 8192 + n0 * 128);
            }
        }
        const char* bufc = smem + cur * 40960;
        const f16* a_s = (const f16*)bufc;
        const f16* b_s = (const f16*)(bufc + 8192);
        __builtin_amdgcn_s_setprio(1);
#pragma unroll
        for (int kk = 0; kk < 2; ++kk) {
            const int kb = kk * 4 + g;
            f16x8 af[4], bf[4];
#pragma unroll
            for (int mi = 0; mi < 4; ++mi) {
                int m = mi * 16 + t_l;
                af[mi] = *(const f16x8*)(a_s + m * 64 + ((kb ^ (m & 7)) * 8));
            }
#pragma unroll
            for (int ni = 0; ni < 4; ++ni) {
                int n = w * 64 + ni * 16 + t_l;
                bf[ni] = *(const f16x8*)(b_s + n * 64 + ((kb ^ (n & 7)) * 8));
            }
#pragma unroll
            for (int mi = 0; mi < 4; ++mi)
#pragma unroll
                for (int ni = 0; ni < 4; ++ni)
                    acc[mi][ni] = __builtin_amdgcn_mfma_f32_16x16x32_f16(af[mi], bf[ni], acc[mi][ni], 0, 0, 0);
        }
        __builtin_amdgcn_s_setprio(0);
        __syncthreads();
        cur ^= 1;
    }

    float* y_s = (float*)smem;
#pragma unroll
    for (int mi = 0; mi < 4; ++mi)
#pragma unroll
        for (int ni = 0; ni < 4; ++ni) {
            int nn = w * 64 + ni * 16 + t_l;
            int xx = nn >> 4, tt = nn & 15;
            int ob = mi * 16 + g * 4;
#pragma unroll
            for (int r2 = 0; r2 < 4; ++r2)
                y_s[(ob + r2) * 273 + xx * 17 + tt] = acc[mi][ni][r2];
        }
    __syncthreads();
#pragma unroll
    for (int k = 0; k < 4; ++k) {
        int pair = k * 256 + tid;          // 0..1023
        int o = pair >> 4, t = pair & 15;
        float bias = pb[oc * 64 + o];
        float v[16];
#pragma unroll
        for (int xx = 0; xx < 16; ++xx) v[xx] = y_s[o * 273 + xx * 17 + t] + bias;
        size_t addr = (((size_t)b * 512 + oc * 64 + o) * 16 + t) * 2048 + win * 16;
#pragma unroll
        for (int v4 = 0; v4 < 4; ++v4) {
            float4 ov = {v[v4 * 4 + 0], v[v4 * 4 + 1], v[v4 * 4 + 2], v[v4 * 4 + 3]};
            *(float4*)(out + addr + v4 * 4) = ov;
        }
    }
}

// ================= FALLBACK PATH (fp32, proven) =================

__global__ __launch_bounds__(256) void k_qkv_attn(const float* __restrict__ x,
                                                  const float* __restrict__ qkv_w,
                                                  const float* __restrict__ sc,
                                                  const float* __restrict__ qbias,
                                                  const float* __restrict__ pos_emb,
                                                  float* __restrict__ out) {
    const int h  = blockIdx.x;
    const int x0 = blockIdx.y * 4;
    const int b  = blockIdx.z;
    const int tid = threadIdx.x;

    __shared__ float a_s[192][68];
    __shared__ float b_s[64][68];
    __shared__ float w_s[4][16][17];

    const int ty = tid >> 3;
    const int tx = tid & 7;

    float acc[6][8];
#pragma unroll
    for (int j = 0; j < 6; ++j)
#pragma unroll
        for (int k = 0; k < 8; ++k) acc[j][k] = 0.f;

    for (int ko = 0; ko < 512; ko += 64) {
        __syncthreads();
#pragma unroll
        for (int it = 0; it < 12; ++it) {
            int idx = it * 256 + tid;
            int m = idx >> 4;
            int c4 = (idx & 15) * 4;
            int g = m >> 6, i = m & 63;
            int o = g * 512 + h * 64 + i;
            float4 w4 = *(const float4*)(qkv_w + (size_t)o * 512 + ko + c4);
            float4 s4 = *(const float4*)(sc + b * 512 + ko + c4);
            float ksc = (g == 1) ? 0.125f : 1.0f;
            float4 v;
            v.x = w4.x * s4.x * ksc; v.y = w4.y * s4.y * ksc;
            v.z = w4.z * s4.z * ksc; v.w = w4.w * s4.w * ksc;
            *(float4*)&a_s[m][c4] = v;
        }
#pragma unroll
        for (int it = 0; it < 4; ++it) {
            int idx = it * 256 + tid;
            int cc = idx >> 4, t = idx & 15;
            float4 v = *(const float4*)(x + ((size_t)((b * 512 + ko + cc) * 16 + t)) * 2048 + x0);
            *(float4*)&b_s[cc][t * 4] = v;
        }
        __syncthreads();
#pragma unroll 4
        for (int cc = 0; cc < 64; ++cc) {
            float av[6];
#pragma unroll
            for (int j = 0; j < 6; ++j) av[j] = a_s[ty * 6 + j][cc];
            float4 b0 = *(const float4*)&b_s[cc][tx * 8];
            float4 b1 = *(const float4*)&b_s[cc][tx * 8 + 4];
            float bv[8] = {b0.x, b0.y, b0.z, b0.w, b1.x, b1.y, b1.z, b1.w};
#pragma unroll
            for (int j = 0; j < 6; ++j)
#pragma unroll
                for (int k = 0; k < 8; ++k)
                    acc[j][k] = fmaf(av[j], bv[k], acc[j][k]);
        }
    }
#pragma unroll
    for (int j = 0; j < 6; ++j) {
        int m = ty * 6 + j;
        int o = (m >> 6) * 512 + h * 64 + (m & 63);
        float qb = qbias[b * 1536 + o];
#pragma unroll
        for (int k = 0; k < 8; ++k) acc[j][k] += qb;
    }
    __syncthreads();
#pragma unroll
    for (int j = 0; j < 6; ++j)
#pragma unroll
        for (int k = 0; k < 8; ++k)
            a_s[ty * 6 + j][tx * 8 + k] = acc[j][k];
    __syncthreads();

    {
        const int xx = tid >> 6;
        const int t  = (tid >> 2) & 15;
        const int uq = tid & 3;
        float l[4] = {0.f, 0.f, 0.f, 0.f};
        for (int i = 0; i < 64; ++i) {
            float qv = a_s[i][t * 4 + xx];
#pragma unroll
            for (int uu = 0; uu < 4; ++uu)
                l[uu] = fmaf(qv, a_s[64 + i][(uq * 4 + uu) * 4 + xx], l[uu]);
        }
#pragma unroll
        for (int uu = 0; uu < 4; ++uu) {
            int u = uq * 4 + uu;
            w_s[xx][t][u] = l[uu] + pos_emb[h * 32 + t - u + 15];
        }
    }
    __syncthreads();
    if (tid < 64) {
        const int xx = tid >> 4, t = tid & 15;
        float mx = -3.4e38f;
#pragma unroll
        for (int u = 0; u < 16; ++u) mx = fmaxf(mx, w_s[xx][t][u]);
        float ssum = 0.f;
#pragma unroll
        for (int u = 0; u < 16; ++u) {
            float e = __expf(w_s[xx][t][u] - mx);
            w_s[xx][t][u] = e;
            ssum += e;
        }
        float inv = 1.0f / ssum;
#pragma unroll
        for (int u = 0; u < 16; ++u) w_s[xx][t][u] *= inv;
    }
    __syncthreads();
    {
        const int i  = tid & 63;
        const int t4 = tid >> 6;
        float4 varr[16];
#pragma unroll
        for (int u = 0; u < 16; ++u) varr[u] = *(const float4*)&a_s[128 + i][u * 4];
#pragma unroll
        for (int tt = 0; tt < 4; ++tt) {
            int t = t4 * 4 + tt;
            float4 o4 = {0.f, 0.f, 0.f, 0.f};
#pragma unroll
            for (int u = 0; u < 16; ++u) {
                o4.x = fmaf(w_s[0][t][u], varr[u].x, o4.x);
                o4.y = fmaf(w_s[1][t][u], varr[u].y, o4.y);
                o4.z = fmaf(w_s[2][t][u], varr[u].z, o4.z);
                o4.w = fmaf(w_s[3][t][u], varr[u].w, o4.w);
            }
            *(float4*)(out + ((size_t)((b * 512 + h * 64 + i) * 16 + t)) * 2048 + x0) = o4;
        }
    }
}

__global__ __launch_bounds__(256) void k_proj(const float* __restrict__ pw,
                                              const float* __restrict__ pb,
                                              float* __restrict__ io) {
    const int n0 = blockIdx.x * 32;
    const int b  = blockIdx.y;
    const int tid = threadIdx.x;
    __shared__ float in_s[512][36];
    __shared__ float w_s[128][65];

    {
        const float* src = io + (size_t)b * 512 * 32768 + n0;
#pragma unroll
        for (int it = 0; it < 64; ++it) {
            int idx = it * 256 + tid;
            int r = idx >> 5, j = idx & 31;
            in_s[r][j] = src[(size_t)r * 32768 + j];
        }
    }
    __syncthreads();

    const int ty = tid >> 3;
    const int tx = tid & 7;

    for (int mo = 0; mo < 512; mo += 128) {
        float acc[4][4];
#pragma unroll
        for (int j = 0; j < 4; ++j)
#pragma unroll
            for (int k = 0; k < 4; ++k) acc[j][k] = 0.f;

        for (int ko = 0; ko < 512; ko += 64) {
#pragma unroll
            for (int it = 0; it < 32; ++it) {
                int idx = it * 256 + tid;
                int m = idx >> 6, cc = idx & 63;
                w_s[m][cc] = pw[(size_t)(mo + m) * 512 + ko + cc];
            }
            __syncthreads();
#pragma unroll 4
            for (int cc = 0; cc < 64; ++cc) {
                float4 bv = *(const float4*)&in_s[ko + cc][tx * 4];
                float a0 = w_s[ty * 4 + 0][cc];
                float a1 = w_s[ty * 4 + 1][cc];
                float a2 = w_s[ty * 4 + 2][cc];
                float a3 = w_s[ty * 4 + 3][cc];
                acc[0][0] = fmaf(a0, bv.x, acc[0][0]); acc[0][1] = fmaf(a0, bv.y, acc[0][1]);
                acc[0][2] = fmaf(a0, bv.z, acc[0][2]); acc[0][3] = fmaf(a0, bv.w, acc[0][3]);
                acc[1][0] = fmaf(a1, bv.x, acc[1][0]); acc[1][1] = fmaf(a1, bv.y, acc[1][1]);
                acc[1][2] = fmaf(a1, bv.z, acc[1][2]); acc[1][3] = fmaf(a1, bv.w, acc[1][3]);
                acc[2][0] = fmaf(a2, bv.x, acc[2][0]); acc[2][1] = fmaf(a2, bv.y, acc[2][1]);
                acc[2][2] = fmaf(a2, bv.z, acc[2][2]); acc[2][3] = fmaf(a2, bv.w, acc[2][3]);
                acc[3][0] = fmaf(a3, bv.x, acc[3][0]); acc[3][1] = fmaf(a3, bv.y, acc[3][1]);
                acc[3][2] = fmaf(a3, bv.z, acc[3][2]); acc[3][3] = fmaf(a3, bv.w, acc[3][3]);
            }
            __syncthreads();
        }
#pragma unroll
        for (int j = 0; j < 4; ++j) {
            int m = mo + ty * 4 + j;
            float bias = pb[m];
            float4 o4 = {acc[j][0] + bias, acc[j][1] + bias, acc[j][2] + bias, acc[j][3] + bias};
            *(float4*)(io + (size_t)(b * 512 + m) * 32768 + n0 + tx * 4) = o4;
        }
    }
}

extern "C" void kernel_launch(void* const* d_in, const int* in_sizes, int n_in,
                              void* d_out, int out_size, void* d_ws, size_t ws_size,
                              hipStream_t stream) {
    (void)in_sizes; (void)n_in; (void)out_size;
    const float* x       = (const float*)d_in[0];
    const float* gn_w    = (const float*)d_in[1];
    const float* gn_b    = (const float*)d_in[2];
    const float* qkv_w   = (const float*)d_in[3];
    const float* qkv_b   = (const float*)d_in[4];
    const float* proj_w  = (const float*)d_in[5];
    const float* proj_b  = (const float*)d_in[6];
    const float* pos_emb = (const float*)d_in[7];
    float* out = (float*)d_out;

    float* ws    = (float*)d_ws;
    float* psum  = ws;            // 2048 (T2/T3)
    float* psq   = ws + 2048;     // 2048
    float* mu    = ws + 4096;     // 128
    float* rs    = ws + 4224;     // 128
    float* sc    = ws + 4352;     // 2048
    float* beta  = ws + 6400;     // 2048
    float* qbias = ws + 8448;     // 6144

    const size_t XT_BYTES = (size_t)4 * 2048 * 16 * 512 * 2;   // 134.2 MB

    // T1 layout
    const size_t W16B_OFF = 65536;
    const size_t P16B_OFF = W16B_OFF + (size_t)4 * 1536 * 512 * 2;
    const size_t XT1_OFF  = P16B_OFF + (size_t)512 * 512 * 2;
    const size_t AT1_OFF  = XT1_OFF + XT_BYTES;
    const size_t NEED_T1  = AT1_OFF + XT_BYTES;

    // T2 layout
    const size_t W16_OFF = 65536;
    const size_t P16_OFF = W16_OFF + (size_t)1536 * 512 * 2;
    const size_t XT2_OFF = P16_OFF + (size_t)512 * 512 * 2;
    const size_t AT2_OFF = XT2_OFF + XT_BYTES;
    const size_t NEED_T2 = AT2_OFF + XT_BYTES;

    const int K_LDS = 81920;
    hipError_t a1 = hipFuncSetAttribute((const void*)k3_mfma,
                                        hipFuncAttributeMaxDynamicSharedMemorySize, K_LDS);
    hipError_t a2 = hipFuncSetAttribute((const void*)k4x,
                                        hipFuncAttributeMaxDynamicSharedMemorySize, K_LDS);

    if (ws_size >= NEED_T1 && a1 == hipSuccess && a2 == hipSuccess) {
        f16* w16b  = (f16*)((char*)d_ws + W16B_OFF);
        f16* p16   = (f16*)((char*)d_ws + P16B_OFF);
        f16* xT    = (f16*)((char*)d_ws + XT1_OFF);
        f16* attnT = (f16*)((char*)d_ws + AT1_OFF);
        float* psum2 = (float*)((char*)d_ws + AT1_OFF);            // overlay (pre-k3 lifetime)
        float* psq2  = (float*)((char*)d_ws + AT1_OFF + 262144);
        k_xtstat<<<dim3(32, 8, 64), dim3(256), 0, stream>>>(x, xT, psum2, psq2);
        k_gn_final2<<<dim3(1), dim3(128), 0, stream>>>(psum2, psq2, mu, rs);
        k_fold_sc<<<dim3(8), dim3(256), 0, stream>>>(gn_w, gn_b, mu, rs, sc, beta);
        k_fold_bias<<<dim3(24), dim3(256), 0, stream>>>(qkv_w, qkv_b, beta, qbias);
        k_prep_wb<<<dim3(768, 4), dim3(256), 0, stream>>>(qkv_w, sc, w16b);
        k_prep_p<<<dim3(256), dim3(256), 0, stream>>>(proj_w, p16);
        k3_mfma<<<dim3(8, 256, 4), dim3(256), K_LDS, stream>>>(xT, w16b, (size_t)786432,
                                                               qkv_b, qbias, pos_emb, out, attnT);
        k4x<<<dim3(8, 128, 4), dim3(256), K_LDS, stream>>>(attnT, p16, proj_b, out);
    } else if (ws_size >= NEED_T2 && a1 == hipSuccess && a2 == hipSuccess) {
        f16* w16   = (f16*)((char*)d_ws + W16_OFF);
        f16* p16   = (f16*)((char*)d_ws + P16_OFF);
        f16* xT    = (f16*)((char*)d_ws + XT2_OFF);
        f16* attnT = (f16*)((char*)d_ws + AT2_OFF);
        k_gn_part<<<dim3(2048), dim3(256), 0, stream>>>(x, psum, psq);
        k_gn_final<<<dim3(1), dim3(128), 0, stream>>>(psum, psq, mu, rs);
        k_fold_sc<<<dim3(8), dim3(256), 0, stream>>>(gn_w, gn_b, mu, rs, sc, beta);
        k_prep_w<<<dim3(1024), dim3(256), 0, stream>>>(qkv_w, proj_w, w16, p16);
        k_xt<<<dim3(32, 8, 64), dim3(256), 0, stream>>>(x, sc, beta, xT);
        k3_mfma<<<dim3(8, 256, 4), dim3(256), K_LDS, stream>>>(xT, w16, (size_t)0,
                                                               qkv_b, nullptr, pos_emb, out, attnT);
        k4x<<<dim3(8, 128, 4), dim3(256), K_LDS, stream>>>(attnT, p16, proj_b, out);
    } else {
        k_gn_part<<<dim3(2048), dim3(256), 0, stream>>>(x, psum, psq);
        k_gn_final<<<dim3(1), dim3(128), 0, stream>>>(psum, psq, mu, rs);
        k_fold_sc<<<dim3(8), dim3(256), 0, stream>>>(gn_w, gn_b, mu, rs, sc, beta);
        k_fold_bias<<<dim3(24), dim3(256), 0, stream>>>(qkv_w, qkv_b, beta, qbias);
        k_qkv_attn<<<dim3(8, 512, 4), dim3(256), 0, stream>>>(x, qkv_w, sc, qbias, pos_emb, out);
        k_proj<<<dim3(1024, 4), dim3(256), 0, stream>>>(proj_w, proj_b, out);
    }
}